// Round 10
// baseline (203.071 us; speedup 1.0000x reference)
//
#include <hip/hip_runtime.h>
#include <math.h>

#define B_ 8
#define S_ 2048
#define F_ 64
#define D_ 512
#define NS_ 5
#define BS_ (B_*S_)
#define NTILE_ 528
#define NPART_ (NTILE_*B_)

typedef unsigned short u16;
typedef __attribute__((ext_vector_type(8))) short short8;
typedef __attribute__((ext_vector_type(4))) float f32x4;

// float-region offsets (in floats)
#define WS_SQ    0
#define WS_REL   (BS_)
#define WS_PE    (4*BS_)       // k2 partials [0,16896); bf16 w_proj at +20480 (u16 view)
#define WS_WPB   (WS_PE + 20480)
#define WS_STATS (68*BS_)
#define US_BASE_FLOATS (68*BS_ + 16)
// ushort-region offsets (in ushorts, from usb)
#define US_XB 0
#define US_QB (BS_*64)
#define US_KB (2*BS_*64)
#define US_XT (3*BS_*64)

#define MFMA16(a,b,c) __builtin_amdgcn_mfma_f32_16x16x32_bf16(a,b,c,0,0,0)

__device__ __forceinline__ u16 f2bf(float f){
  unsigned u = __float_as_uint(f);
  return (u16)((u + 0x7FFFu + ((u>>16)&1u)) >> 16);
}
__device__ __forceinline__ float b2f(short s){
  return __uint_as_float(((unsigned)(unsigned short)s) << 16);
}
// f32-tile swizzle used by k1
__device__ __forceinline__ int swz_phys(int row, int c){ return row*64 + (((c ^ (row & 15))) << 2); }

// K1: q/k (fp32 compute -> bf16 store), sq, rel sums, xb16, xT16, w_proj bf16 (blocks 0..31)
__global__ __launch_bounds__(256) void k1_prep(
    const float* __restrict__ x, const float* __restrict__ wq, const float* __restrict__ bq,
    const float* __restrict__ wk, const float* __restrict__ bk,
    const float* __restrict__ scale_w, const float* __restrict__ wp,
    float* __restrict__ ws, u16* __restrict__ usb, u16* __restrict__ wpb)
{
  __shared__ __align__(16) float xl[16*68];
  __shared__ __align__(16) float wql[4096];
  __shared__ __align__(16) float wkl[4096];
  int tid = threadIdx.x, lane = tid & 63, wv = tid >> 6;
  int row0 = blockIdx.x * 16;
  {
    int r = tid >> 4, c = tid & 15;
    *(float4*)(xl + r*68 + c*4) = *(const float4*)(x + (size_t)(row0 + r)*F_ + c*4);
  }
  for (int i = 0; i < 4; ++i){
    int idx = tid + i*256;
    int g = idx >> 4, c = idx & 15;
    float4 v = *(const float4*)(wq + g*F_ + c*4);
    int pb = swz_phys(g, c);
    wql[pb]=v.x; wql[pb+1]=v.y; wql[pb+2]=v.z; wql[pb+3]=v.w;
    float4 u = *(const float4*)(wk + g*F_ + c*4);
    wkl[pb]=u.x; wkl[pb+1]=u.y; wkl[pb+2]=u.z; wkl[pb+3]=u.w;
  }
  // w_proj bf16 conversion (independent work, blocks 0..31)
  if (blockIdx.x < 32){
    int i2 = (blockIdx.x*256 + tid)*4;
    float4 v = *(const float4*)(wp + i2);
    uint2 pk2;
    pk2.x = (unsigned)f2bf(v.x) | ((unsigned)f2bf(v.y)<<16);
    pk2.y = (unsigned)f2bf(v.z) | ((unsigned)f2bf(v.w)<<16);
    *(uint2*)(wpb + i2) = pk2;
  }
  __syncthreads();
  int g = lane;
  int swl = g & 15;
  float qa[4], ka[4];
  #pragma unroll
  for (int j=0;j<4;++j){ qa[j]=bq[g]; ka[j]=bk[g]; }
  #pragma unroll
  for (int c=0;c<16;++c){
    float4 wqv = *(const float4*)(wql + g*64 + ((c ^ swl)<<2));
    float4 wkv = *(const float4*)(wkl + g*64 + ((c ^ swl)<<2));
    #pragma unroll
    for (int j=0;j<4;++j){
      float4 xv = *(const float4*)(xl + (wv*4+j)*68 + c*4);
      qa[j] += xv.x*wqv.x + xv.y*wqv.y + xv.z*wqv.z + xv.w*wqv.w;
      ka[j] += xv.x*wkv.x + xv.y*wkv.y + xv.z*wkv.z + xv.w*wkv.w;
    }
  }
  #pragma unroll
  for (int j=0;j<4;++j){
    int rg = row0 + wv*4 + j;
    usb[US_QB + (size_t)rg*64 + g] = f2bf(qa[j]);
    usb[US_KB + (size_t)rg*64 + g] = f2bf(ka[j]);
  }
  #pragma unroll
  for (int j=0;j<4;++j){
    int r = wv*4 + j;
    float v = xl[r*68 + lane];
    float s = v*v;
    for (int o=32;o;o>>=1) s += __shfl_xor(s, o, 64);
    if (lane == 0) ws[WS_SQ + row0 + r] = s;
  }
  #pragma unroll
  for (int j=0;j<4;++j){
    int r = wv*4 + j;
    int rg = row0 + r;
    int b = rg >> 11, s_loc = rg & (S_-1);
    float d0 = xl[r*68 + 0], e0 = xl[r*68 + 1];
    float dd = 0.f, de = 0.f, wd = 0.f;
    int n = lane + 1;
    if (lane < NS_ && s_loc >= n){
      const float* xp = x + ((size_t)(b*S_ + s_loc - n))*F_;
      float dp_ = xp[0], ep = xp[1];
      dd = dp_ - d0;
      de = ep - e0;
      wd = scale_w[lane] * __expf(-fabsf(dd) * (1.0f/(float)(1<<n)));
    }
    for (int o=4;o;o>>=1){
      dd += __shfl_down(dd, o, 64);
      de += __shfl_down(de, o, 64);
      wd += __shfl_down(wd, o, 64);
    }
    if (lane == 0){
      ws[WS_REL + rg*3+0] = dd;
      ws[WS_REL + rg*3+1] = de;
      ws[WS_REL + rg*3+2] = wd;
    }
  }
  // bf16 x (row-major)
  {
    int r = tid >> 4, cb = (tid & 15)*4;
    unsigned w0 = (unsigned)f2bf(xl[r*68+cb])   | ((unsigned)f2bf(xl[r*68+cb+1])<<16);
    unsigned w1 = (unsigned)f2bf(xl[r*68+cb+2]) | ((unsigned)f2bf(xl[r*68+cb+3])<<16);
    uint2 pk; pk.x = w0; pk.y = w1;
    *(uint2*)(usb + US_XB + (size_t)(row0+r)*64 + cb) = pk;
  }
  // bf16 x transposed per batch: xT[b][f][t]
  {
    int f = tid & 63, rg4 = (tid >> 6)*4;
    unsigned wa = (unsigned)f2bf(xl[(rg4+0)*68+f]) | ((unsigned)f2bf(xl[(rg4+1)*68+f])<<16);
    unsigned wb = (unsigned)f2bf(xl[(rg4+2)*68+f]) | ((unsigned)f2bf(xl[(rg4+3)*68+f])<<16);
    uint2 pk; pk.x = wa; pk.y = wb;
    int bb = row0 >> 11;
    int tloc = (row0 & (S_-1)) + rg4;
    *(uint2*)(usb + US_XT + (size_t)bb*64*2048 + (size_t)f*2048 + tloc) = pk;
  }
}

// K2: euclid stats via MFMA Gram, upper-triangle tiles only (off-diag weight 2).
__global__ __launch_bounds__(256) void k2_stats(const u16* __restrict__ us, float* __restrict__ ws)
{
  __shared__ __align__(16) u16 Xls[4096];
  __shared__ float sqs_l[64], sqt_l[64];
  __shared__ float rsum[4], rss[4], rmn[4], rmx[4];
  int tid = threadIdx.x, lane = tid & 63, wv = tid >> 6;
  int lg = lane >> 4, lc = lane & 15;
  int b = blockIdx.y;
  int rem = blockIdx.x, i = 0;
  while (rem >= 32 - i){ rem -= 32 - i; ++i; }
  int j = i + rem;
  int s0 = i*64, t0 = j*64;
  size_t rb = (size_t)b * S_;
  const u16* xb = us + US_XB;
  #pragma unroll
  for (int p2=0;p2<2;++p2){
    int slot = tid + p2*256;
    int row = slot>>3, pc = slot&7, lcn = pc ^ (row&7);
    ((short8*)Xls)[slot] = *(const short8*)(xb + (rb + t0 + row)*64 + lcn*8);
  }
  if (tid < 64) sqs_l[tid] = ws[WS_SQ + rb + s0 + tid];
  else if (tid < 128) sqt_l[tid-64] = ws[WS_SQ + rb + t0 + (tid-64)];
  short8 a0 = *(const short8*)(xb + (rb + s0 + wv*16 + lc)*64 + lg*8);
  short8 a1 = *(const short8*)(xb + (rb + s0 + wv*16 + lc)*64 + 32 + lg*8);
  __syncthreads();
  f32x4 acc[4];
  #pragma unroll
  for (int t=0;t<4;++t){ acc[t][0]=0.f; acc[t][1]=0.f; acc[t][2]=0.f; acc[t][3]=0.f; }
  #pragma unroll
  for (int ts=0; ts<4; ++ts){
    int rowb = ts*16 + lc;
    int sw = rowb & 7;
    short8 b0 = *(const short8*)(Xls + rowb*64 + ((lg ^ sw)<<3));
    short8 b1 = *(const short8*)(Xls + rowb*64 + (((4+lg) ^ sw)<<3));
    acc[ts] = MFMA16(a0, b0, acc[ts]);
    acc[ts] = MFMA16(a1, b1, acc[ts]);
  }
  float sq_s[4];
  #pragma unroll
  for (int r=0;r<4;++r) sq_s[r] = sqs_l[wv*16 + lg*4 + r];
  float lsum=0.f, lss=0.f, lmn=3.4e38f, lmx=-3.4e38f;
  #pragma unroll
  for (int ts=0; ts<4; ++ts){
    float sqt = sqt_l[ts*16 + lc];
    #pragma unroll
    for (int r=0;r<4;++r){
      float gg = acc[ts][r];
      float d2 = sq_s[r] + sqt - 2.f*gg;
      d2 = fmaxf(d2, 0.f);
      float eu = d2 > 0.f ? sqrtf(d2) : 0.f;
      lsum += eu; lss += eu*eu;
      lmn = fminf(lmn, eu); lmx = fmaxf(lmx, eu);
    }
  }
  for (int o=32;o;o>>=1){
    lsum += __shfl_xor(lsum, o, 64);
    lss  += __shfl_xor(lss, o, 64);
    lmn = fminf(lmn, __shfl_xor(lmn, o, 64));
    lmx = fmaxf(lmx, __shfl_xor(lmx, o, 64));
  }
  if (lane == 0){ rsum[wv]=lsum; rss[wv]=lss; rmn[wv]=lmn; rmx[wv]=lmx; }
  __syncthreads();
  if (tid == 0){
    float bs=0.f, bss=0.f, bmn=3.4e38f, bmx=-3.4e38f;
    for (int w2=0;w2<4;++w2){ bs+=rsum[w2]; bss+=rss[w2]; bmn=fminf(bmn,rmn[w2]); bmx=fmaxf(bmx,rmx[w2]); }
    float wgt = (i==j) ? 1.f : 2.f;
    float* part = ws + WS_PE;
    int bid = blockIdx.y * NTILE_ + blockIdx.x;
    part[bid]           = bs*wgt;
    part[NPART_ + bid]  = bss*wgt;
    part[2*NPART_ + bid]= bmn;
    part[3*NPART_ + bid]= bmx;
  }
}

// K3: reduce k2 partials + finalize folded scalar constants
__global__ __launch_bounds__(256) void k3_fin(const float* __restrict__ alpha,
                                              const float* __restrict__ sigma_w, float* ws){
  __shared__ double ssm[256], sss[256];
  __shared__ float smn[256], smx[256];
  int tid = threadIdx.x;
  const float* part = ws + WS_PE;
  double s = 0.0, ss = 0.0;
  float mn = 3.4e38f, mx = -3.4e38f;
  for (int i2 = tid; i2 < NPART_; i2 += 256){
    s  += (double)part[i2];
    ss += (double)part[NPART_ + i2];
    mn = fminf(mn, part[2*NPART_ + i2]);
    mx = fmaxf(mx, part[3*NPART_ + i2]);
  }
  ssm[tid]=s; sss[tid]=ss; smn[tid]=mn; smx[tid]=mx;
  __syncthreads();
  for (int st = 128; st; st >>= 1){
    if (tid < st){
      ssm[tid] += ssm[tid+st];
      sss[tid] += sss[tid+st];
      smn[tid] = fminf(smn[tid], smn[tid+st]);
      smx[tid] = fmaxf(smx[tid], smx[tid+st]);
    }
    __syncthreads();
  }
  if (tid == 0){
    double N = (double)B_*S_*S_;
    double sum = ssm[0], sumsq = sss[0];
    double mean = sum/N;
    double var  = (sumsq - sum*sum/N) / (N - 1.0);
    float stdv = (float)sqrt(fmax(var, 0.0));
    float m = (float)mean;
    float lo = m - 2.f*stdv, hi = m + 2.f*stdv;
    float cmn = fminf(fmaxf(smn[0], lo), hi);
    float cmx = fminf(fmaxf(smx[0], lo), hi);
    float invr = 1.f/(cmx - cmn + 1e-6f);
    float a = 1.f/(1.f + expf(-alpha[0]));
    float oma = 1.f - a;
    float swv = sigma_w[0];
    float sp = (swv > 20.f) ? swv : log1pf(expf(swv));
    float sg = sp + 0.001f;
    float efac = -0.5f/(sg*sg);
    float cg = efac*a*0.5f;
    float ce = -efac*oma*invr;
    float cc = efac*(a*0.5f + oma + oma*invr*cmn);
    float* p = ws + WS_STATS + 8;
    p[0]=lo; p[1]=hi; p[2]=cg; p[3]=ce; p[4]=cc;
  }
}

// K4: MFMA flash pass, t-split (grid.z = 4): each block does a quarter of the K-tiles.
// Partials into the owning k5-block's d_out slice (8192 floats):
//   bf16 pe-partials: u16 view, u16-offset rowblk*16384 + h*1024 + row16*64 + f   [floats 0..2048)
//   f32 z-partials:   float-offset rowblk*8192 + 2048 + h*16 + row16              [floats 2048..2112)
__global__ __launch_bounds__(512) void k4_flash(const u16* __restrict__ us,
                                                const float* __restrict__ ws,
                                                float* __restrict__ outsc)
{
  __shared__ __align__(16) u16 SMEM[16384];  // Kls|Xls|XTls|el : 4x8KB
  __shared__ float sqt_l[64], invt_l[64];
  __shared__ float zb[4][2][16];
  u16* Kls  = SMEM;
  u16* Xls  = SMEM + 4096;
  u16* XTls = SMEM + 8192;
  u16* elp  = SMEM + 12288;
  int tid = threadIdx.x, lane = tid & 63, wv = tid >> 6;
  int lg = lane >> 4, lc = lane & 15;
  int ssub = wv >> 1, th = wv & 1;
  int b = blockIdx.y;
  int h = blockIdx.z;
  size_t rb = (size_t)b * S_;
  int s0 = blockIdx.x * 64;
  const u16* xb = us + US_XB;
  const u16* qb = us + US_QB;
  const u16* kb = us + US_KB;
  const u16* xt = us + US_XT + (size_t)b*64*2048;
  int srow = s0 + ssub*16 + lc;
  short8 qf0 = *(const short8*)(qb + (rb+srow)*64 + lg*8);
  short8 qf1 = *(const short8*)(qb + (rb+srow)*64 + 32 + lg*8);
  short8 xf0 = *(const short8*)(xb + (rb+srow)*64 + lg*8);
  short8 xf1 = *(const short8*)(xb + (rb+srow)*64 + 32 + lg*8);
  const float* prm = ws + WS_STATS + 8;
  float lo=prm[0], hi=prm[1], cg=prm[2], ce=prm[3], cc=prm[4];
  float sq_s[4], cgis[4];
  #pragma unroll
  for (int r=0;r<4;++r){
    float s = ws[WS_SQ + rb + s0 + ssub*16 + lg*4 + r];
    sq_s[r] = s;
    cgis[r] = cg / fmaxf(sqrtf(s), 1e-12f);
  }
  f32x4 pe[4];
  #pragma unroll
  for (int t=0;t<4;++t){ pe[t][0]=0.f; pe[t][1]=0.f; pe[t][2]=0.f; pe[t][3]=0.f; }
  float zrun[4];
  #pragma unroll
  for (int r=0;r<4;++r) zrun[r]=0.f;

  int tbeg = h * (S_/4), tend = tbeg + (S_/4);
  for (int t0 = tbeg; t0 < tend; t0 += 64){
    {
      int slot = tid;
      int row = slot>>3, pc = slot&7, lcn = pc ^ (row&7);
      ((short8*)Kls)[slot]  = *(const short8*)(kb + (rb + t0 + row)*64 + lcn*8);
      ((short8*)Xls)[slot]  = *(const short8*)(xb + (rb + t0 + row)*64 + lcn*8);
      ((short8*)XTls)[slot] = *(const short8*)(xt + (size_t)row*2048 + t0 + lcn*8);
    }
    if (tid < 64){
      float s = ws[WS_SQ + rb + t0 + tid];
      sqt_l[tid] = s;
      invt_l[tid] = 1.f / fmaxf(sqrtf(s), 1e-12f);
    }
    __syncthreads();
    f32x4 ga[2], sa[2];
    #pragma unroll
    for (int t=0;t<2;++t){ ga[t][0]=0.f; ga[t][1]=0.f; ga[t][2]=0.f; ga[t][3]=0.f;
                           sa[t][0]=0.f; sa[t][1]=0.f; sa[t][2]=0.f; sa[t][3]=0.f; }
    #pragma unroll
    for (int ts=0; ts<2; ++ts){
      int rowb = (2*th+ts)*16 + lc;
      int sw = rowb & 7;
      short8 bk0 = *(const short8*)(Kls + rowb*64 + ((lg ^ sw)<<3));
      short8 bx0 = *(const short8*)(Xls + rowb*64 + ((lg ^ sw)<<3));
      sa[ts] = MFMA16(qf0, bk0, sa[ts]);
      ga[ts] = MFMA16(xf0, bx0, ga[ts]);
      short8 bk1 = *(const short8*)(Kls + rowb*64 + (((4+lg) ^ sw)<<3));
      short8 bx1 = *(const short8*)(Xls + rowb*64 + (((4+lg) ^ sw)<<3));
      sa[ts] = MFMA16(qf1, bk1, sa[ts]);
      ga[ts] = MFMA16(xf1, bx1, ga[ts]);
    }
    #pragma unroll
    for (int ts=0; ts<2; ++ts){
      int col = (2*th+ts)*16 + lc;
      float sqt = sqt_l[col], invt = invt_l[col];
      #pragma unroll
      for (int r=0;r<4;++r){
        float gg = ga[ts][r];
        float d2 = fmaxf(__builtin_fmaf(-2.f, gg, sq_s[r] + sqt), 0.f);
        float eu = fminf(fmaxf(sqrtf(d2), lo), hi);
        float arg = __builtin_fmaf(cgis[r]*invt, gg, cc);
        arg = __builtin_fmaf(ce, eu, arg);
        float s8 = __builtin_fmaf(sa[ts][r], 0.125f, -8.f);
        float p = __expf(s8);
        float pH = __expf(arg + s8);
        zrun[r] += p;
        int rowl = lg*4 + r;
        int phys = rowl*64 + ((((col>>3) ^ (rowl&7)))<<3) + (col&7);
        elp[ssub*1024 + phys] = f2bf(pH);
      }
    }
    // PV: pe[fs] += E(16x32 window) @ x(32 x 16f)
    {
      int swA = lc & 7;
      short8 Ae = *(const short8*)(elp + ssub*1024 + lc*64 + (((4*th + lg) ^ swA)<<3));
      #pragma unroll
      for (int fs=0; fs<4; ++fs){
        int rowf = fs*16 + lc;
        short8 Bx = *(const short8*)(XTls + rowf*64 + (((4*th + lg) ^ (rowf&7))<<3));
        pe[fs] = MFMA16(Ae, Bx, pe[fs]);
      }
    }
    __syncthreads();
  }
  // z reduce (per row, over this block's t-quarter)
  #pragma unroll
  for (int r=0;r<4;++r){
    float z = zrun[r];
    z += __shfl_xor(z, 1, 64);
    z += __shfl_xor(z, 2, 64);
    z += __shfl_xor(z, 4, 64);
    z += __shfl_xor(z, 8, 64);
    if (lc == r) zb[ssub][th][lg*4+r] = z;
  }
  __syncthreads();
  float* tmp = (float*)SMEM;  // 4096 floats scratch (tiles dead now)
  if (th == 1){
    #pragma unroll
    for (int fs=0; fs<4; ++fs)
      #pragma unroll
      for (int r=0;r<4;++r)
        tmp[ssub*1024 + (lg*4+r)*64 + fs*16 + lc] = pe[fs][r];
  }
  __syncthreads();
  if (th == 0){
    size_t rowblk = ((rb + (size_t)s0) >> 4) + ssub;     // k5-block index
    u16* scp = (u16*)outsc + rowblk*16384 + (size_t)h*1024;
    #pragma unroll
    for (int fs=0; fs<4; ++fs)
      #pragma unroll
      for (int r=0;r<4;++r){
        float v = pe[fs][r] + tmp[ssub*1024 + (lg*4+r)*64 + fs*16 + lc];
        scp[(lg*4+r)*64 + fs*16 + lc] = f2bf(v);
      }
    if (lg == 0)
      outsc[rowblk*8192 + 2048 + h*16 + lc] = zb[ssub][0][lc] + zb[ssub][1][lc];
  }
}

// K5: combine 4 bf16 pe-partials + z from scratch (in d_out), MFMA pe_proj +
// both LayerNorms + add. Partial reads all precede the barrier; output writes follow it.
__global__ __launch_bounds__(256) void k5_final(
    const float* __restrict__ w_rel, const float* __restrict__ b_rel,
    const float* __restrict__ b_proj,
    const float* __restrict__ g1, const float* __restrict__ bt1,
    const float* __restrict__ g2, const float* __restrict__ bt2,
    const float* __restrict__ ws, const u16* __restrict__ wpb, float* out)
{
  __shared__ __align__(16) float res[16*512];
  __shared__ float rsl[48];
  __shared__ float g1l[512], b1l[512], g2l[512], b2l[512], brl[512], wrl[1536];
  int tid = threadIdx.x, lane = tid & 63, wv = tid >> 6;
  int lg = lane >> 4, lc = lane & 15;
  int row0 = blockIdx.x * 16;
  size_t base5 = (size_t)blockIdx.x * 8192;
  const u16* pb = (const u16*)out + (size_t)blockIdx.x * 16384;
  float zi = 1.f / (out[base5+2048+lc] + out[base5+2048+16+lc]
                  + out[base5+2048+32+lc] + out[base5+2048+48+lc]);
  short8 a0, a1;
  {
    int off0 = lc*64 + lg*8;
    short8 h0 = *(const short8*)(pb + off0);
    short8 h1 = *(const short8*)(pb + 1024 + off0);
    short8 h2 = *(const short8*)(pb + 2048 + off0);
    short8 h3 = *(const short8*)(pb + 3072 + off0);
    #pragma unroll
    for (int e=0;e<8;++e)
      a0[e] = (short)f2bf((b2f(h0[e]) + b2f(h1[e]) + b2f(h2[e]) + b2f(h3[e])) * zi);
    int off1 = off0 + 32;
    short8 j0 = *(const short8*)(pb + off1);
    short8 j1 = *(const short8*)(pb + 1024 + off1);
    short8 j2 = *(const short8*)(pb + 2048 + off1);
    short8 j3 = *(const short8*)(pb + 3072 + off1);
    #pragma unroll
    for (int e=0;e<8;++e)
      a1[e] = (short)f2bf((b2f(j0[e]) + b2f(j1[e]) + b2f(j2[e]) + b2f(j3[e])) * zi);
  }
  if (tid < 48) rsl[tid] = ws[WS_REL + row0*3 + tid];
  for (int i = tid; i < 512; i += 256){
    g1l[i]=g1[i]; b1l[i]=bt1[i]; g2l[i]=g2[i]; b2l[i]=bt2[i]; brl[i]=b_rel[i];
  }
  for (int i = tid; i < 1536; i += 256) wrl[i] = w_rel[i];
  int wc0 = wv*128;
  #pragma unroll
  for (int cgi=0; cgi<8; ++cgi){
    int d = wc0 + cgi*16 + lc;
    short8 b0 = *(const short8*)(wpb + (size_t)d*64 + lg*8);
    short8 b1 = *(const short8*)(wpb + (size_t)d*64 + 32 + lg*8);
    f32x4 acc = {0.f,0.f,0.f,0.f};
    acc = MFMA16(a0, b0, acc);
    acc = MFMA16(a1, b1, acc);
    float bp = b_proj[d];
    #pragma unroll
    for (int r=0;r<4;++r) res[(lg*4+r)*512 + d] = acc[r] + bp;
  }
  __syncthreads();
  #pragma unroll
  for (int j=0;j<4;++j){
    int r = wv*4 + j;
    int rg = row0 + r;
    float s1=0.f, q1=0.f;
    float vals[8];
    #pragma unroll
    for (int i=0;i<8;++i){ float v = res[r*512 + i*64 + lane]; vals[i]=v; s1+=v; q1+=v*v; }
    for (int o=32;o;o>>=1){ s1 += __shfl_xor(s1,o,64); q1 += __shfl_xor(q1,o,64); }
    float mu1 = s1*(1.f/512.f);
    float var1 = q1*(1.f/512.f) - mu1*mu1;
    float rsg1 = rsqrtf(fmaxf(var1, 0.f) + 1e-5f);
    float c0 = rsl[r*3+0], c1 = rsl[r*3+1], c2 = rsl[r*3+2];
    float rv[8]; float s2=0.f, q2=0.f;
    #pragma unroll
    for (int i=0;i<8;++i){
      int d = i*64 + lane;
      float v = c0*wrl[d*3+0] + c1*wrl[d*3+1] + c2*wrl[d*3+2] + 5.f*brl[d];
      rv[i]=v; s2+=v; q2+=v*v;
    }
    for (int o=32;o;o>>=1){ s2 += __shfl_xor(s2,o,64); q2 += __shfl_xor(q2,o,64); }
    float mu2 = s2*(1.f/512.f);
    float var2 = q2*(1.f/512.f) - mu2*mu2;
    float rsg2 = rsqrtf(fmaxf(var2, 0.f) + 1e-5f);
    #pragma unroll
    for (int i=0;i<8;++i){
      int d = i*64 + lane;
      float o1 = (vals[i]-mu1)*rsg1*g2l[d] + b2l[d];
      float o2 = (rv[i]-mu2)*rsg2*g1l[d] + b1l[d];
      out[(size_t)rg*512 + d] = o1 + o2;
    }
  }
}

extern "C" void kernel_launch(void* const* d_in, const int* in_sizes, int n_in,
                              void* d_out, int out_size, void* d_ws, size_t ws_size,
                              hipStream_t stream)
{
  const float* x      = (const float*)d_in[0];
  const float* w_rel  = (const float*)d_in[1];
  const float* b_rel  = (const float*)d_in[2];
  const float* w_proj = (const float*)d_in[3];
  const float* b_proj = (const float*)d_in[4];
  const float* g1     = (const float*)d_in[5];
  const float* bt1    = (const float*)d_in[6];
  const float* g2     = (const float*)d_in[7];
  const float* bt2    = (const float*)d_in[8];
  const float* alpha  = (const float*)d_in[9];
  const float* sigma_w= (const float*)d_in[10];
  const float* wq     = (const float*)d_in[11];
  const float* bq     = (const float*)d_in[12];
  const float* wk     = (const float*)d_in[13];
  const float* bk     = (const float*)d_in[14];
  const float* scale_w= (const float*)d_in[15];
  float* wsf = (float*)d_ws;
  u16*  usb = (u16*)(wsf + US_BASE_FLOATS);
  u16*  wpb = (u16*)(wsf + WS_WPB);
  float* out = (float*)d_out;

  hipLaunchKernelGGL(k1_prep, dim3(BS_/16), dim3(256), 0, stream,
                     x, wq, bq, wk, bk, scale_w, w_proj, wsf, usb, wpb);
  hipLaunchKernelGGL(k2_stats, dim3(NTILE_, B_), dim3(256), 0, stream, usb, wsf);
  hipLaunchKernelGGL(k3_fin, dim3(1), dim3(256), 0, stream, alpha, sigma_w, wsf);
  hipLaunchKernelGGL(k4_flash, dim3(S_/64, B_, 4), dim3(512), 0, stream, usb, wsf, out);
  hipLaunchKernelGGL(k5_final, dim3(BS_/16), dim3(256), 0, stream,
                     w_rel, b_rel, b_proj, g1, bt1, g2, bt2, wsf, wpb, out);
}